// Round 3
// baseline (1764.655 us; speedup 1.0000x reference)
//
#include <hip/hip_runtime.h>
#include <math.h>

#define BB 128
#define T2 2050
#define TT 2049
#define HH 64
#define GG 448   // 7*H
#define KK 100
#define NE 103   // K+3

#define LOG2E 1.44269504088896340736f
#define LN2   0.69314718055994530942f

__device__ __forceinline__ float frcp(float x) { return __builtin_amdgcn_rcpf(x); }
__device__ __forceinline__ float sigmoid_fast(float x) {
    return frcp(1.f + exp2f(-x * LOG2E));
}
__device__ __forceinline__ float tanh_fast(float x) {
    float e = exp2f(x * (2.f * LOG2E));
    return 1.f - 2.f * frcp(1.f + e);
}
__device__ __forceinline__ float softplus_fast(float x) {
    float t = exp2f(-fabsf(x) * LOG2E);
    return fmaxf(x, 0.f) + LN2 * log2f(1.f + t);
}
// broadcast h[k] from lane k of own wave (VALU readlane, const lane idx)
__device__ __forceinline__ float rl(float v, int k) {
    return __int_as_float(__builtin_amdgcn_readlane(__float_as_int(v), k));
}

// pre_emb[e][g] = sum_k in_emb[e][k] * Wx[k][g] + bias[g]   (103 x 448)
__global__ void pre_emb_kernel(const float* __restrict__ in_emb,
                               const float* __restrict__ Wx,
                               const float* __restrict__ bias,
                               float* __restrict__ pre_emb) {
    int e = blockIdx.x;
    int g = threadIdx.x;
    float acc = bias[g];
#pragma unroll
    for (int k = 0; k < HH; ++k)
        acc = fmaf(in_emb[e * HH + k], Wx[k * GG + g], acc);
    pre_emb[e * GG + g] = acc;
}

// One block per batch row; 4 waves (256 threads), 1 wave/SIMD.
// State h/c/cb is REPLICATED per wave (lane i holds element i) — the
// matvec broadcasts h via v_readlane (VALU) instead of LDS, and every wave
// redundantly applies the state update, so only the 448 gate values cross
// waves (gbuf, double-buffered) and only ONE barrier per step is needed.
// Dots: all threads gate tid; waves 0-2 also gate 256+tid; wave 3 also
// logit[lane] and (lanes<36) logit[64+lane], written raw to a 64-slot LDS
// ring, softplus'd+flushed to global every 32 steps in phase 2.
__launch_bounds__(256, 1)
__global__ void scan_kernel(const int* __restrict__ event,
                            const float* __restrict__ dtime,
                            const float* __restrict__ pre_emb,
                            const float* __restrict__ Wh,
                            const float* __restrict__ out_emb,
                            float* __restrict__ out) {
    const int b    = blockIdx.x;
    const int tid  = threadIdx.x;
    const int w    = tid >> 6;
    const int lane = tid & 63;
    const bool isw3 = (w == 3);

    __shared__ float gbuf[2][GG];
    __shared__ float obuf[64 * 128];   // 32 KB logit ring (raw logits)

    float w1[HH], w2[HH], w3r[HH];
#pragma unroll
    for (int k = 0; k < HH; ++k) w1[k] = Wh[k * GG + tid];
    if (!isw3) {
#pragma unroll
        for (int k = 0; k < HH; ++k) w2[k] = Wh[k * GG + 256 + tid];
    } else {
#pragma unroll
        for (int k = 0; k < HH; ++k) w2[k] = out_emb[lane * HH + k];
#pragma unroll
        for (int k = 0; k < HH; ++k)
            w3r[k] = (lane < 36) ? out_emb[(64 + lane) * HH + k] : 0.f;
    }

    float h = 0.f, c = 0.f, cb = 0.f;

    const int*   ev_row  = event + b * T2;
    const float* dt_row  = dtime + b * T2;
    float*       out_row = out + (size_t)b * TT * KK;

    int   ev0 = ev_row[0];
    float pe1 = pre_emb[ev0 * GG + tid];
    float pe2 = isw3 ? 0.f : pre_emb[ev0 * GG + 256 + tid];
    int   evn = ev_row[1];
    float dtc = dt_row[1];

    for (int t = 0; t < TT; ++t) {
        const int buf = t & 1;
        // ---- phase 1: prefetch next step, compute dots, write gbuf/obuf
        const int tp = (t + 2 <= T2 - 1) ? (t + 2) : (T2 - 1);
        float pe1n = pre_emb[evn * GG + tid];
        float pe2n = isw3 ? 0.f : pre_emb[evn * GG + 256 + tid];
        int   evnn = ev_row[tp];
        float dtn  = dt_row[tp];

        float a1 = pe1, a2 = pe2, a3 = 0.f;
        if (isw3) {
#pragma unroll
            for (int k = 0; k < HH; ++k) {
                float s = rl(h, k);
                a1 = fmaf(s, w1[k], a1);
                a2 = fmaf(s, w2[k], a2);
                a3 = fmaf(s, w3r[k], a3);
            }
        } else {
#pragma unroll
            for (int k = 0; k < HH; ++k) {
                float s = rl(h, k);
                a1 = fmaf(s, w1[k], a1);
                a2 = fmaf(s, w2[k], a2);
            }
        }

        float v1 = (w == 2) ? tanh_fast(a1) : sigmoid_fast(a1);
        gbuf[buf][tid] = v1;
        if (!isw3) {
            float v2 = (w == 2) ? softplus_fast(a2) : sigmoid_fast(a2);
            gbuf[buf][256 + tid] = v2;
        } else if (t > 0) {
            const int slot = (t - 1) & 63;     // logits of h_{t-1} -> output t-1
            obuf[slot * 128 + lane] = a2;
            if (lane < 36) obuf[slot * 128 + 64 + lane] = a3;
        }
        __syncthreads();

        // ---- phase 2: redundant state update (all waves), periodic flush
        const float gi  = gbuf[buf][lane];
        const float gf  = gbuf[buf][64 + lane];
        const float gz  = gbuf[buf][128 + lane];
        const float go  = gbuf[buf][192 + lane];
        const float gib = gbuf[buf][256 + lane];
        const float gfb = gbuf[buf][320 + lane];
        const float gd  = gbuf[buf][384 + lane];
        const float ci  = fmaf(gf, c, gi * gz);
        const float cbi = fmaf(gfb, cb, gib * gz);
        const float cn  = fmaf(ci - cbi, exp2f(-gd * dtc * LOG2E), cbi);
        h  = go * tanh_fast(cn);
        c  = cn;
        cb = cbi;
        dtc = dtn; pe1 = pe1n; pe2 = pe2n; evn = evnn;

        if (t >= 34 && (t & 31) == 2) {
            const int base = t - 34;           // outputs base..base+31 ready
            const int s0   = base & 63;        // 0 or 32, no wrap
#pragma unroll
            for (int j = 0; j < 16; ++j) {
                const int g   = j * 256 + tid;
                const int row = g >> 7, col = g & 127;
                if (col < KK)
                    out_row[(size_t)(base + row) * KK + col] =
                        softplus_fast(obuf[(s0 + row) * 128 + col]);
            }
        }
    }

    // ---- tail: flush outputs 2016..2047 (slots 32..63), then output 2048
    {
        const int base = 2016, s0 = 32;
#pragma unroll
        for (int j = 0; j < 16; ++j) {
            const int g   = j * 256 + tid;
            const int row = g >> 7, col = g & 127;
            if (col < KK)
                out_row[(size_t)(base + row) * KK + col] =
                    softplus_fast(obuf[(s0 + row) * 128 + col]);
        }
        if (isw3) {   // h now holds h_{T-1}
            float a2 = 0.f, a3 = 0.f;
#pragma unroll
            for (int k = 0; k < HH; ++k) {
                float s = rl(h, k);
                a2 = fmaf(s, w2[k], a2);
                a3 = fmaf(s, w3r[k], a3);
            }
            out_row[(size_t)(TT - 1) * KK + lane] = softplus_fast(a2);
            if (lane < 36)
                out_row[(size_t)(TT - 1) * KK + 64 + lane] = softplus_fast(a3);
        }
    }
}

extern "C" void kernel_launch(void* const* d_in, const int* in_sizes, int n_in,
                              void* d_out, int out_size, void* d_ws, size_t ws_size,
                              hipStream_t stream) {
    const int*   event  = (const int*)d_in[0];
    const float* dtime  = (const float*)d_in[1];
    const float* in_emb = (const float*)d_in[2];
    const float* Wx     = (const float*)d_in[3];
    const float* Wh     = (const float*)d_in[4];
    const float* bias   = (const float*)d_in[5];
    const float* oe     = (const float*)d_in[6];
    float*       out    = (float*)d_out;

    float* pre_emb = (float*)d_ws;  // 103*448*4 = 184,576 bytes

    pre_emb_kernel<<<NE, GG, 0, stream>>>(in_emb, Wx, bias, pre_emb);
    scan_kernel<<<BB, 256, 0, stream>>>(event, dtime, pre_emb, Wh, oe, out);
}